// Round 19
// baseline (219.092 us; speedup 1.0000x reference)
//
#include <hip/hip_runtime.h>
#include <hip/hip_fp16.h>

#define F_IN 512
#define HID  16
#define NCLS 40
#define KSPL 4
#define KH   (F_IN / KSPL)   // 128
#define GNOD 128             // nodes per gemm block (x4 parts = 512 threads)
#define RSTR 65              // odd LDS reduction stride -> conflict-free
#define BSH2 8            // 256 nodes per bucket
#define BNODES 256
#define NBMAX 512         // >= nbuckets = 391
#define EPB 8192          // edges per bhist/bucket block
#define CAP 12288         // LDS row buffer capacity (mean 8184, sigma~90)

__device__ __forceinline__ void ld_h8(const __half* p, float* f) {
    uint4 u = *reinterpret_cast<const uint4*>(p);
    __half2 a = *reinterpret_cast<__half2*>(&u.x);
    __half2 b = *reinterpret_cast<__half2*>(&u.y);
    __half2 c = *reinterpret_cast<__half2*>(&u.z);
    __half2 d = *reinterpret_cast<__half2*>(&u.w);
    float2 fa = __half22float2(a), fb = __half22float2(b);
    float2 fc = __half22float2(c), fd = __half22float2(d);
    f[0] = fa.x; f[1] = fa.y; f[2] = fb.x; f[3] = fb.y;
    f[4] = fc.x; f[5] = fc.y; f[6] = fd.x; f[7] = fd.y;
}

__device__ __forceinline__ void st_h8(__half* p, const float* f) {
    __half2 a = __floats2half2_rn(f[0], f[1]);
    __half2 b = __floats2half2_rn(f[2], f[3]);
    __half2 c = __floats2half2_rn(f[4], f[5]);
    __half2 d = __floats2half2_rn(f[6], f[7]);
    uint4 u;
    u.x = *reinterpret_cast<unsigned*>(&a);
    u.y = *reinterpret_cast<unsigned*>(&b);
    u.z = *reinterpret_cast<unsigned*>(&c);
    u.w = *reinterpret_cast<unsigned*>(&d);
    *reinterpret_cast<uint4*>(p) = u;
}

__device__ __forceinline__ void st_h4(__half* p, float4 v) {
    __half2 a = __floats2half2_rn(v.x, v.y);
    __half2 b = __floats2half2_rn(v.z, v.w);
    uint2 u;
    u.x = *reinterpret_cast<unsigned*>(&a);
    u.y = *reinterpret_cast<unsigned*>(&b);
    *reinterpret_cast<uint2*>(p) = u;
}

__device__ __forceinline__ float4 ld_h4(const __half* p) {
    uint2 u = *reinterpret_cast<const uint2*>(p);
    __half2 a = *reinterpret_cast<__half2*>(&u.x);
    __half2 b = *reinterpret_cast<__half2*>(&u.y);
    float2 fa = __half22float2(a), fb = __half22float2(b);
    return make_float4(fa.x, fa.y, fb.x, fb.y);
}

// Fat kernel: blocks [0,neb) = bucket histogram -> lhists.
// blocks [neb,...) = GEMM: 128 nodes x 4 wave-uniform K-parts, LDS-reduced,
// unscaled fp16 yp written directly.
__global__ __launch_bounds__(512) void k_front(
    const int* __restrict__ col, int* __restrict__ lhists,
    const float* __restrict__ x, const float* __restrict__ W1,
    __half* __restrict__ yp, int ne, int n, int neb) {
    __shared__ float red[GNOD * RSTR];   // 33.3 KB; aliased as int lh[] for hist
    int t = threadIdx.x;
    if (blockIdx.x < neb) {
        int* lh = (int*)red;
        lh[t] = 0;
        __syncthreads();
        int base = blockIdx.x * EPB;
        int end = min(ne, base + EPB);
        int e = base + t * 4;
        for (; e + 3 < end; e += 2048) {
            int4 c = *reinterpret_cast<const int4*>(col + e);
            atomicAdd(&lh[c.x >> BSH2], 1);
            atomicAdd(&lh[c.y >> BSH2], 1);
            atomicAdd(&lh[c.z >> BSH2], 1);
            atomicAdd(&lh[c.w >> BSH2], 1);
        }
        for (; e < end; ++e) atomicAdd(&lh[col[e] >> BSH2], 1);
        __syncthreads();
        lhists[(size_t)blockIdx.x * NBMAX + t] = lh[t];
        return;
    }
    int fb = blockIdx.x - neb;
    int part = __builtin_amdgcn_readfirstlane(t >> 7);   // wave-uniform K slice
    int nl = t & 127;
    int node = fb * GNOD + nl;
    bool alive = node < n;
    float acc[HID];
#pragma unroll
    for (int j = 0; j < HID; ++j) acc[j] = 0.f;
    if (alive) {
        const float* xr = x + (size_t)node * F_IN + part * KH;
        const float* Wb = W1 + (size_t)part * KH * HID;
#define STEP(av, kk) \
    _Pragma("unroll") for (int j = 0; j < HID; ++j) acc[j] = fmaf(av, w[(kk) * HID + j], acc[j]);
#pragma unroll
        for (int k = 0; k < KH; k += 16) {
            const float4* xv = reinterpret_cast<const float4*>(xr + k);
            float4 a0 = xv[0], a1 = xv[1], a2 = xv[2], a3 = xv[3];
            const float* w = Wb + (size_t)k * HID;
            STEP(a0.x, 0)  STEP(a0.y, 1)  STEP(a0.z, 2)  STEP(a0.w, 3)
            STEP(a1.x, 4)  STEP(a1.y, 5)  STEP(a1.z, 6)  STEP(a1.w, 7)
            STEP(a2.x, 8)  STEP(a2.y, 9)  STEP(a2.z, 10) STEP(a2.w, 11)
            STEP(a3.x, 12) STEP(a3.y, 13) STEP(a3.z, 14) STEP(a3.w, 15)
        }
    }
    float* r = red + nl * RSTR + part * HID;
#pragma unroll
    for (int j = 0; j < HID; ++j) r[j] = acc[j];
    __syncthreads();
    int nl2 = t >> 2;
    int node2 = fb * GNOD + nl2;
    if (node2 < n) {
        int q = (t & 3) << 2;
        const float* rb = red + nl2 * RSTR;
        float s0 = rb[q]     + rb[HID + q]     + rb[2 * HID + q]     + rb[3 * HID + q];
        float s1 = rb[q + 1] + rb[HID + q + 1] + rb[2 * HID + q + 1] + rb[3 * HID + q + 1];
        float s2 = rb[q + 2] + rb[HID + q + 2] + rb[2 * HID + q + 2] + rb[3 * HID + q + 2];
        float s3 = rb[q + 3] + rb[HID + q + 3] + rb[2 * HID + q + 3] + rb[3 * HID + q + 3];
        st_h4(yp + (size_t)node2 * HID + q, make_float4(s0, s1, s2, s3));
    }
}

// column-sum lhists -> bucket totals, then exclusive scan -> bstart, bcur
__global__ __launch_bounds__(512) void k_bscan(
    const int* __restrict__ lhists, int* __restrict__ bstart,
    int* __restrict__ bcur, int nb, int neb) {
    __shared__ int sh[512];
    int t = threadIdx.x;
    int s = 0;
#pragma unroll 4
    for (int j = 0; j < neb; ++j) s += lhists[(size_t)j * NBMAX + t];
    int v = (t < nb) ? s : 0;
    sh[t] = v;
    __syncthreads();
    for (int off = 1; off < 512; off <<= 1) {
        int u = (t >= off) ? sh[t - off] : 0;
        __syncthreads();
        sh[t] += u;
        __syncthreads();
    }
    if (t < nb) {
        int ex = sh[t] - v;
        bstart[t] = ex;
        bcur[t] = ex;
    }
    if (t == nb - 1) bstart[nb] = sh[t];
}

// LDS counting sort per 8192-edge block; histogram precomputed in lhists
__global__ __launch_bounds__(512) void k_bucket(
    const int* __restrict__ row, const int* __restrict__ col,
    const int* __restrict__ lhists, int* __restrict__ bcur,
    int* __restrict__ packed, int ne) {
    __shared__ int lbase[NBMAX];
    __shared__ int gbase[NBMAX];
    __shared__ int lcur[NBMAX];
    __shared__ int buf[EPB];
    __shared__ unsigned short bof[EPB];
    int t = threadIdx.x;
    int own = lhists[(size_t)blockIdx.x * NBMAX + t];
    lcur[t] = 0;
    if (own > 0) gbase[t] = atomicAdd(&bcur[t], own);
    lbase[t] = own;
    __syncthreads();
    for (int off = 1; off < 512; off <<= 1) {
        int v = (t >= off) ? lbase[t - off] : 0;
        __syncthreads();
        lbase[t] += v;
        __syncthreads();
    }
    int ex = lbase[t] - own;
    __syncthreads();
    lbase[t] = ex;
    __syncthreads();
    int base = blockIdx.x * EPB;
    int end = min(ne, base + EPB);
    for (int e = base + t; e < end; e += 512) {
        int r = row[e], c = col[e];
        int gb = c >> BSH2;
        int rk = atomicAdd(&lcur[gb], 1);
        int pos = lbase[gb] + rk;
        buf[pos] = r | ((c & (BNODES - 1)) << 24);
        bof[pos] = (unsigned short)gb;
    }
    __syncthreads();
    int m = end - base;
    for (int k = t; k < m; k += 512) {
        int gb = bof[k];
        packed[gbase[gb] + (k - lbase[gb])] = buf[k];
    }
}

// per-bucket CSR finalize: count -> cnt/ptr; scale yp in place (fused k_scale);
// LDS-scatter -> coalesced rows_sorted
__global__ __launch_bounds__(512) void k_csr(
    int* __restrict__ cnt, const int* __restrict__ bstart,
    const int* __restrict__ packed, int* __restrict__ ptr,
    int* __restrict__ rows_sorted, __half* __restrict__ yp, int n, int nb) {
    __shared__ int sh[BNODES];
    __shared__ int cl[BNODES];
    __shared__ int lcur[BNODES];
    __shared__ int lrows[CAP];
    int b = blockIdx.x, t = threadIdx.x;
    int c0 = b << BSH2;
    int nloc = min(BNODES, n - c0);
    int s = bstart[b], e = bstart[b + 1];
    int m = e - s;
    if (t < BNODES) sh[t] = 0;
    __syncthreads();
    for (int k = t; k < m; k += 512)
        atomicAdd(&sh[((unsigned)packed[s + k]) >> 24], 1);
    __syncthreads();
    int own = (t < BNODES) ? sh[t] : 0;
    if (t < BNODES) cl[t] = own;
    if (t < nloc) cnt[c0 + t] = own;
    for (int off = 1; off < BNODES; off <<= 1) {
        int v = (t >= off && t < BNODES) ? sh[t - off] : 0;
        __syncthreads();
        if (t < BNODES) sh[t] += v;
        __syncthreads();
    }
    if (t < nloc) {
        int ex = sh[t] - own;
        ptr[c0 + t] = s + ex;
        lcur[t] = ex;
    }
    if (b == nb - 1 && t == 0) ptr[n] = e;
    __syncthreads();
    // fused scale: yp[node] *= dinv for this bucket's nodes (2 x 16B slots/node)
    for (int i = t; i < nloc * 2; i += 512) {
        int nl = i >> 1;
        float di = rsqrtf((float)(cl[nl] + 1));
        __half* p = yp + (size_t)(c0 + nl) * HID + (i & 1) * 8;
        float f[8];
        ld_h8(p, f);
#pragma unroll
        for (int j = 0; j < 8; ++j) f[j] *= di;
        st_h8(p, f);
    }
    if (m <= CAP) {
        for (int k = t; k < m; k += 512) {
            int p = packed[s + k];
            int pos = atomicAdd(&lcur[((unsigned)p) >> 24], 1);
            lrows[pos] = p & 0xFFFFFF;
        }
        __syncthreads();
        for (int k = t; k < m; k += 512) rows_sorted[s + k] = lrows[k];
    } else {
        for (int k = t; k < m; k += 512) {
            int p = packed[s + k];
            int pos = atomicAdd(&lcur[((unsigned)p) >> 24], 1);
            rows_sorted[s + pos] = p & 0xFFFFFF;
        }
    }
}

// Gather-reduce over CSR segment: 2 lanes/node, 16B gathers, fp32 accumulate.
template <bool RELU>
__global__ void k_agg(const int* __restrict__ ptr, const int* __restrict__ rows_sorted,
                      const __half* __restrict__ src, const int* __restrict__ cnt,
                      const float* __restrict__ b1,
                      __half* __restrict__ dst_h, float* __restrict__ dst_f, int n) {
    int t = blockIdx.x * blockDim.x + threadIdx.x;
    int g = t >> 1;
    if (g >= n) return;
    int q = (t & 1) << 3;   // 0 or 8
    float acc[8];
    ld_h8(src + (size_t)g * HID + q, acc);
    int s = ptr[g], e2 = ptr[g + 1];
    int k = s;
    for (; k + 3 < e2; k += 4) {
        int r0 = rows_sorted[k],     r1 = rows_sorted[k + 1];
        int r2 = rows_sorted[k + 2], r3 = rows_sorted[k + 3];
        float v0[8], v1[8], v2[8], v3[8];
        ld_h8(src + (size_t)r0 * HID + q, v0);
        ld_h8(src + (size_t)r1 * HID + q, v1);
        ld_h8(src + (size_t)r2 * HID + q, v2);
        ld_h8(src + (size_t)r3 * HID + q, v3);
#pragma unroll
        for (int j = 0; j < 8; ++j)
            acc[j] += (v0[j] + v1[j]) + (v2[j] + v3[j]);
    }
    for (; k < e2; ++k) {
        int r0 = rows_sorted[k];
        float v0[8];
        ld_h8(src + (size_t)r0 * HID + q, v0);
#pragma unroll
        for (int j = 0; j < 8; ++j) acc[j] += v0[j];
    }
    float d = rsqrtf((float)(cnt[g] + 1));
    if (RELU) {
        float bb[8];
        float4 b0 = *reinterpret_cast<const float4*>(b1 + q);
        float4 b4 = *reinterpret_cast<const float4*>(b1 + q + 4);
        bb[0] = b0.x; bb[1] = b0.y; bb[2] = b0.z; bb[3] = b0.w;
        bb[4] = b4.x; bb[5] = b4.y; bb[6] = b4.z; bb[7] = b4.w;
        float o[8];
#pragma unroll
        for (int j = 0; j < 8; ++j)
            o[j] = d * fmaxf(fmaf(d, acc[j], bb[j]), 0.f);
        st_h8(dst_h + (size_t)g * HID + q, o);
    } else {
        float* o = dst_f + (size_t)g * HID + q;
        *reinterpret_cast<float4*>(o) = make_float4(d * acc[0], d * acc[1], d * acc[2], d * acc[3]);
        *reinterpret_cast<float4*>(o + 4) = make_float4(d * acc[4], d * acc[5], d * acc[6], d * acc[7]);
    }
}

// out = log_softmax(agg2 @ W2 + b2)
__global__ void k_final(const float* __restrict__ agg2, const float* __restrict__ W2,
                        const float* __restrict__ b2, float* __restrict__ out, int n) {
    int node = blockIdx.x * blockDim.x + threadIdx.x;
    if (node >= n) return;
    const float4* ar = reinterpret_cast<const float4*>(agg2 + (size_t)node * HID);
    float a[HID];
#pragma unroll
    for (int q = 0; q < 4; ++q) {
        float4 t = ar[q];
        a[4 * q] = t.x; a[4 * q + 1] = t.y; a[4 * q + 2] = t.z; a[4 * q + 3] = t.w;
    }
    float z[NCLS];
#pragma unroll
    for (int j = 0; j < NCLS; ++j) z[j] = b2[j];
#pragma unroll
    for (int i = 0; i < HID; ++i) {
        const float* w = W2 + (size_t)i * NCLS;
        float ai = a[i];
#pragma unroll
        for (int j = 0; j < NCLS; ++j) z[j] = fmaf(ai, w[j], z[j]);
    }
    float m = z[0];
#pragma unroll
    for (int j = 1; j < NCLS; ++j) m = fmaxf(m, z[j]);
    float s = 0.f;
#pragma unroll
    for (int j = 0; j < NCLS; ++j) s += __expf(z[j] - m);
    float ls = m + __logf(s);
    float* o = out + (size_t)node * NCLS;
#pragma unroll
    for (int q = 0; q < NCLS / 4; ++q)
        *reinterpret_cast<float4*>(o + 4 * q) =
            make_float4(z[4 * q] - ls, z[4 * q + 1] - ls, z[4 * q + 2] - ls, z[4 * q + 3] - ls);
}

extern "C" void kernel_launch(void* const* d_in, const int* in_sizes, int n_in,
                              void* d_out, int out_size, void* d_ws, size_t ws_size,
                              hipStream_t stream) {
    const float* x  = (const float*)d_in[0];
    const int*   ei = (const int*)d_in[1];
    const float* W1 = (const float*)d_in[2];
    const float* b1 = (const float*)d_in[3];
    const float* W2 = (const float*)d_in[4];
    const float* b2 = (const float*)d_in[5];
    float* out = (float*)d_out;

    const int N = in_sizes[0] / F_IN;   // 100000
    const int E = in_sizes[1] / 2;      // 3200000
    const int* row = ei;
    const int* col = ei + E;
    const int NBUCK = (N + BNODES - 1) >> BSH2;   // 391
    const int NEB = (E + EPB - 1) / EPB;          // 391 edge blocks
    const int GB2 = (N + GNOD - 1) / GNOD;        // 782 gemm blocks

    char* w = (char*)d_ws;
    int*   cnt    = (int*)w;   w += (size_t)N * 4;
    int*   bstart = (int*)w;   w += (size_t)(NBMAX + 1) * 4;
    int*   bcur   = (int*)w;   w += (size_t)NBMAX * 4;
    int*   lhists = (int*)w;   w += (size_t)NEB * NBMAX * 4;
    int*   ptr    = (int*)w;   w += (size_t)(N + 1) * 4;
    int*   rows_sorted = (int*)w; w += (size_t)E * 4;
    int*   packed = (int*)w;   w += (size_t)E * 4;
    __half* yp_h  = (__half*)w; w += (size_t)N * HID * 2;
    __half* hp_h  = (__half*)w; w += (size_t)N * HID * 2;
    float* agg2   = (float*)w; w += (size_t)N * HID * 4;

    const int B = 256;
    k_front <<<NEB + GB2, 512, 0, stream>>>(col, lhists, x, W1, yp_h, E, N, NEB);
    k_bscan <<<1, 512, 0, stream>>>(lhists, bstart, bcur, NBUCK, NEB);
    k_bucket<<<NEB, 512, 0, stream>>>(row, col, lhists, bcur, packed, E);
    k_csr   <<<NBUCK, 512, 0, stream>>>(cnt, bstart, packed, ptr, rows_sorted, yp_h, N, NBUCK);
    k_agg<true> <<<((N * 2) + B - 1) / B, B, 0, stream>>>(ptr, rows_sorted, yp_h, cnt, b1, hp_h, nullptr, N);
    k_agg<false><<<((N * 2) + B - 1) / B, B, 0, stream>>>(ptr, rows_sorted, hp_h, cnt, nullptr, nullptr, agg2, N);
    k_final <<<(N + B - 1) / B, B, 0, stream>>>(agg2, W2, b2, out, N);
}

// Round 20
// 210.300 us; speedup vs baseline: 1.0418x; 1.0418x over previous
//
#include <hip/hip_runtime.h>
#include <hip/hip_fp16.h>

#define F_IN 512
#define HID  16
#define NCLS 40
#define KSPL 4
#define KH   (F_IN / KSPL)   // 128
#define GNOD 128             // nodes per gemm block (x4 parts = 512 threads)
#define RSTR 65              // odd LDS reduction stride -> conflict-free
#define BSH2 8            // 256 nodes per bucket
#define BNODES 256
#define NBMAX 512         // >= nbuckets = 391
#define EPB 8192          // edges per bhist/bucket block
#define CAP 12288         // LDS row buffer capacity (mean 8184, sigma~90)

__device__ __forceinline__ float4 ld_h4(const __half* p) {
    uint2 u = *reinterpret_cast<const uint2*>(p);
    __half2 a = *reinterpret_cast<__half2*>(&u.x);
    __half2 b = *reinterpret_cast<__half2*>(&u.y);
    float2 fa = __half22float2(a), fb = __half22float2(b);
    return make_float4(fa.x, fa.y, fb.x, fb.y);
}

__device__ __forceinline__ void st_h4(__half* p, float4 v) {
    __half2 a = __floats2half2_rn(v.x, v.y);
    __half2 b = __floats2half2_rn(v.z, v.w);
    uint2 u;
    u.x = *reinterpret_cast<unsigned*>(&a);
    u.y = *reinterpret_cast<unsigned*>(&b);
    *reinterpret_cast<uint2*>(p) = u;
}

__device__ __forceinline__ void ld_h8(const __half* p, float* f) {
    uint4 u = *reinterpret_cast<const uint4*>(p);
    __half2 a = *reinterpret_cast<__half2*>(&u.x);
    __half2 b = *reinterpret_cast<__half2*>(&u.y);
    __half2 c = *reinterpret_cast<__half2*>(&u.z);
    __half2 d = *reinterpret_cast<__half2*>(&u.w);
    float2 fa = __half22float2(a), fb = __half22float2(b);
    float2 fc = __half22float2(c), fd = __half22float2(d);
    f[0] = fa.x; f[1] = fa.y; f[2] = fb.x; f[3] = fb.y;
    f[4] = fc.x; f[5] = fc.y; f[6] = fd.x; f[7] = fd.y;
}

__device__ __forceinline__ void st_h8(__half* p, const float* f) {
    __half2 a = __floats2half2_rn(f[0], f[1]);
    __half2 b = __floats2half2_rn(f[2], f[3]);
    __half2 c = __floats2half2_rn(f[4], f[5]);
    __half2 d = __floats2half2_rn(f[6], f[7]);
    uint4 u;
    u.x = *reinterpret_cast<unsigned*>(&a);
    u.y = *reinterpret_cast<unsigned*>(&b);
    u.z = *reinterpret_cast<unsigned*>(&c);
    u.w = *reinterpret_cast<unsigned*>(&d);
    *reinterpret_cast<uint4*>(p) = u;
}

// Fat kernel: blocks [0,neb) = bucket histogram -> lhists.
// blocks [neb,...) = GEMM: 128 nodes x 4 wave-uniform K-parts, LDS-reduced,
// unscaled fp16 yp written directly.
__global__ __launch_bounds__(512) void k_front(
    const int* __restrict__ col, int* __restrict__ lhists,
    const float* __restrict__ x, const float* __restrict__ W1,
    __half* __restrict__ yp, int ne, int n, int neb) {
    __shared__ float red[GNOD * RSTR];   // 33.3 KB; aliased as int lh[] for hist
    int t = threadIdx.x;
    if (blockIdx.x < neb) {
        int* lh = (int*)red;
        lh[t] = 0;
        __syncthreads();
        int base = blockIdx.x * EPB;
        int end = min(ne, base + EPB);
        int e = base + t * 4;
        for (; e + 3 < end; e += 2048) {
            int4 c = *reinterpret_cast<const int4*>(col + e);
            atomicAdd(&lh[c.x >> BSH2], 1);
            atomicAdd(&lh[c.y >> BSH2], 1);
            atomicAdd(&lh[c.z >> BSH2], 1);
            atomicAdd(&lh[c.w >> BSH2], 1);
        }
        for (; e < end; ++e) atomicAdd(&lh[col[e] >> BSH2], 1);
        __syncthreads();
        lhists[(size_t)blockIdx.x * NBMAX + t] = lh[t];
        return;
    }
    int fb = blockIdx.x - neb;
    int part = __builtin_amdgcn_readfirstlane(t >> 7);   // wave-uniform K slice
    int nl = t & 127;
    int node = fb * GNOD + nl;
    bool alive = node < n;
    float acc[HID];
#pragma unroll
    for (int j = 0; j < HID; ++j) acc[j] = 0.f;
    if (alive) {
        const float* xr = x + (size_t)node * F_IN + part * KH;
        const float* Wb = W1 + (size_t)part * KH * HID;
#define STEP(av, kk) \
    _Pragma("unroll") for (int j = 0; j < HID; ++j) acc[j] = fmaf(av, w[(kk) * HID + j], acc[j]);
#pragma unroll
        for (int k = 0; k < KH; k += 16) {
            const float4* xv = reinterpret_cast<const float4*>(xr + k);
            float4 a0 = xv[0], a1 = xv[1], a2 = xv[2], a3 = xv[3];
            const float* w = Wb + (size_t)k * HID;
            STEP(a0.x, 0)  STEP(a0.y, 1)  STEP(a0.z, 2)  STEP(a0.w, 3)
            STEP(a1.x, 4)  STEP(a1.y, 5)  STEP(a1.z, 6)  STEP(a1.w, 7)
            STEP(a2.x, 8)  STEP(a2.y, 9)  STEP(a2.z, 10) STEP(a2.w, 11)
            STEP(a3.x, 12) STEP(a3.y, 13) STEP(a3.z, 14) STEP(a3.w, 15)
        }
    }
    float* r = red + nl * RSTR + part * HID;
#pragma unroll
    for (int j = 0; j < HID; ++j) r[j] = acc[j];
    __syncthreads();
    int nl2 = t >> 2;
    int node2 = fb * GNOD + nl2;
    if (node2 < n) {
        int q = (t & 3) << 2;
        const float* rb = red + nl2 * RSTR;
        float s0 = rb[q]     + rb[HID + q]     + rb[2 * HID + q]     + rb[3 * HID + q];
        float s1 = rb[q + 1] + rb[HID + q + 1] + rb[2 * HID + q + 1] + rb[3 * HID + q + 1];
        float s2 = rb[q + 2] + rb[HID + q + 2] + rb[2 * HID + q + 2] + rb[3 * HID + q + 2];
        float s3 = rb[q + 3] + rb[HID + q + 3] + rb[2 * HID + q + 3] + rb[3 * HID + q + 3];
        st_h4(yp + (size_t)node2 * HID + q, make_float4(s0, s1, s2, s3));
    }
}

// column-sum lhists -> bucket totals, then exclusive scan -> bstart, bcur
__global__ __launch_bounds__(512) void k_bscan(
    const int* __restrict__ lhists, int* __restrict__ bstart,
    int* __restrict__ bcur, int nb, int neb) {
    __shared__ int sh[512];
    int t = threadIdx.x;
    int s = 0;
#pragma unroll 4
    for (int j = 0; j < neb; ++j) s += lhists[(size_t)j * NBMAX + t];
    int v = (t < nb) ? s : 0;
    sh[t] = v;
    __syncthreads();
    for (int off = 1; off < 512; off <<= 1) {
        int u = (t >= off) ? sh[t - off] : 0;
        __syncthreads();
        sh[t] += u;
        __syncthreads();
    }
    if (t < nb) {
        int ex = sh[t] - v;
        bstart[t] = ex;
        bcur[t] = ex;
    }
    if (t == nb - 1) bstart[nb] = sh[t];
}

// LDS counting sort per 8192-edge block; histogram precomputed in lhists
__global__ __launch_bounds__(512) void k_bucket(
    const int* __restrict__ row, const int* __restrict__ col,
    const int* __restrict__ lhists, int* __restrict__ bcur,
    int* __restrict__ packed, int ne) {
    __shared__ int lbase[NBMAX];
    __shared__ int gbase[NBMAX];
    __shared__ int lcur[NBMAX];
    __shared__ int buf[EPB];
    __shared__ unsigned short bof[EPB];
    int t = threadIdx.x;
    int own = lhists[(size_t)blockIdx.x * NBMAX + t];
    lcur[t] = 0;
    if (own > 0) gbase[t] = atomicAdd(&bcur[t], own);
    lbase[t] = own;
    __syncthreads();
    for (int off = 1; off < 512; off <<= 1) {
        int v = (t >= off) ? lbase[t - off] : 0;
        __syncthreads();
        lbase[t] += v;
        __syncthreads();
    }
    int ex = lbase[t] - own;
    __syncthreads();
    lbase[t] = ex;
    __syncthreads();
    int base = blockIdx.x * EPB;
    int end = min(ne, base + EPB);
    for (int e = base + t; e < end; e += 512) {
        int r = row[e], c = col[e];
        int gb = c >> BSH2;
        int rk = atomicAdd(&lcur[gb], 1);
        int pos = lbase[gb] + rk;
        buf[pos] = r | ((c & (BNODES - 1)) << 24);
        bof[pos] = (unsigned short)gb;
    }
    __syncthreads();
    int m = end - base;
    for (int k = t; k < m; k += 512) {
        int gb = bof[k];
        packed[gbase[gb] + (k - lbase[gb])] = buf[k];
    }
}

// per-bucket CSR finalize: count -> cnt/ptr; scale yp in place (fused);
// LDS-scatter -> coalesced rows_sorted
__global__ __launch_bounds__(512) void k_csr(
    int* __restrict__ cnt, const int* __restrict__ bstart,
    const int* __restrict__ packed, int* __restrict__ ptr,
    int* __restrict__ rows_sorted, __half* __restrict__ yp, int n, int nb) {
    __shared__ int sh[BNODES];
    __shared__ int cl[BNODES];
    __shared__ int lcur[BNODES];
    __shared__ int lrows[CAP];
    int b = blockIdx.x, t = threadIdx.x;
    int c0 = b << BSH2;
    int nloc = min(BNODES, n - c0);
    int s = bstart[b], e = bstart[b + 1];
    int m = e - s;
    if (t < BNODES) sh[t] = 0;
    __syncthreads();
    for (int k = t; k < m; k += 512)
        atomicAdd(&sh[((unsigned)packed[s + k]) >> 24], 1);
    __syncthreads();
    int own = (t < BNODES) ? sh[t] : 0;
    if (t < BNODES) cl[t] = own;
    if (t < nloc) cnt[c0 + t] = own;
    for (int off = 1; off < BNODES; off <<= 1) {
        int v = (t >= off && t < BNODES) ? sh[t - off] : 0;
        __syncthreads();
        if (t < BNODES) sh[t] += v;
        __syncthreads();
    }
    if (t < nloc) {
        int ex = sh[t] - own;
        ptr[c0 + t] = s + ex;
        lcur[t] = ex;
    }
    if (b == nb - 1 && t == 0) ptr[n] = e;
    __syncthreads();
    // fused scale: yp[node] *= dinv for this bucket's nodes (2 x 16B slots/node)
    for (int i = t; i < nloc * 2; i += 512) {
        int nl = i >> 1;
        float di = rsqrtf((float)(cl[nl] + 1));
        __half* p = yp + (size_t)(c0 + nl) * HID + (i & 1) * 8;
        float f[8];
        ld_h8(p, f);
#pragma unroll
        for (int j = 0; j < 8; ++j) f[j] *= di;
        st_h8(p, f);
    }
    if (m <= CAP) {
        for (int k = t; k < m; k += 512) {
            int p = packed[s + k];
            int pos = atomicAdd(&lcur[((unsigned)p) >> 24], 1);
            lrows[pos] = p & 0xFFFFFF;
        }
        __syncthreads();
        for (int k = t; k < m; k += 512) rows_sorted[s + k] = lrows[k];
    } else {
        for (int k = t; k < m; k += 512) {
            int p = packed[s + k];
            int pos = atomicAdd(&lcur[((unsigned)p) >> 24], 1);
            rows_sorted[s + pos] = p & 0xFFFFFF;
        }
    }
}

// Gather-reduce over CSR segment on fp16 rows: 4 lanes/node, 8B gathers,
// fp32 accumulate, 4-edge unroll (R18's proven shape).
template <bool RELU>
__global__ void k_agg(const int* __restrict__ ptr, const int* __restrict__ rows_sorted,
                      const __half* __restrict__ src, const int* __restrict__ cnt,
                      const float* __restrict__ b1,
                      __half* __restrict__ dst_h, float* __restrict__ dst_f, int n) {
    int t = blockIdx.x * blockDim.x + threadIdx.x;
    int g = t >> 2;
    if (g >= n) return;
    int q = (t & 3) << 2;
    float4 acc = ld_h4(src + (size_t)g * HID + q);
    int s = ptr[g], e2 = ptr[g + 1];
    int k = s;
    for (; k + 3 < e2; k += 4) {
        int r0 = rows_sorted[k],     r1 = rows_sorted[k + 1];
        int r2 = rows_sorted[k + 2], r3 = rows_sorted[k + 3];
        float4 v0 = ld_h4(src + (size_t)r0 * HID + q);
        float4 v1 = ld_h4(src + (size_t)r1 * HID + q);
        float4 v2 = ld_h4(src + (size_t)r2 * HID + q);
        float4 v3 = ld_h4(src + (size_t)r3 * HID + q);
        acc.x += (v0.x + v1.x) + (v2.x + v3.x);
        acc.y += (v0.y + v1.y) + (v2.y + v3.y);
        acc.z += (v0.z + v1.z) + (v2.z + v3.z);
        acc.w += (v0.w + v1.w) + (v2.w + v3.w);
    }
    for (; k < e2; ++k) {
        int r0 = rows_sorted[k];
        float4 v0 = ld_h4(src + (size_t)r0 * HID + q);
        acc.x += v0.x; acc.y += v0.y; acc.z += v0.z; acc.w += v0.w;
    }
    float d = rsqrtf((float)(cnt[g] + 1));
    if (RELU) {
        float4 bb = *reinterpret_cast<const float4*>(b1 + q);
        float4 o;
        o.x = d * fmaxf(fmaf(d, acc.x, bb.x), 0.f);
        o.y = d * fmaxf(fmaf(d, acc.y, bb.y), 0.f);
        o.z = d * fmaxf(fmaf(d, acc.z, bb.z), 0.f);
        o.w = d * fmaxf(fmaf(d, acc.w, bb.w), 0.f);
        st_h4(dst_h + (size_t)g * HID + q, o);
    } else {
        float4 o = make_float4(d * acc.x, d * acc.y, d * acc.z, d * acc.w);
        *reinterpret_cast<float4*>(dst_f + (size_t)g * HID + q) = o;
    }
}

// out = log_softmax(agg2 @ W2 + b2)
__global__ void k_final(const float* __restrict__ agg2, const float* __restrict__ W2,
                        const float* __restrict__ b2, float* __restrict__ out, int n) {
    int node = blockIdx.x * blockDim.x + threadIdx.x;
    if (node >= n) return;
    const float4* ar = reinterpret_cast<const float4*>(agg2 + (size_t)node * HID);
    float a[HID];
#pragma unroll
    for (int q = 0; q < 4; ++q) {
        float4 t = ar[q];
        a[4 * q] = t.x; a[4 * q + 1] = t.y; a[4 * q + 2] = t.z; a[4 * q + 3] = t.w;
    }
    float z[NCLS];
#pragma unroll
    for (int j = 0; j < NCLS; ++j) z[j] = b2[j];
#pragma unroll
    for (int i = 0; i < HID; ++i) {
        const float* w = W2 + (size_t)i * NCLS;
        float ai = a[i];
#pragma unroll
        for (int j = 0; j < NCLS; ++j) z[j] = fmaf(ai, w[j], z[j]);
    }
    float m = z[0];
#pragma unroll
    for (int j = 1; j < NCLS; ++j) m = fmaxf(m, z[j]);
    float s = 0.f;
#pragma unroll
    for (int j = 0; j < NCLS; ++j) s += __expf(z[j] - m);
    float ls = m + __logf(s);
    float* o = out + (size_t)node * NCLS;
#pragma unroll
    for (int q = 0; q < NCLS / 4; ++q)
        *reinterpret_cast<float4*>(o + 4 * q) =
            make_float4(z[4 * q] - ls, z[4 * q + 1] - ls, z[4 * q + 2] - ls, z[4 * q + 3] - ls);
}

extern "C" void kernel_launch(void* const* d_in, const int* in_sizes, int n_in,
                              void* d_out, int out_size, void* d_ws, size_t ws_size,
                              hipStream_t stream) {
    const float* x  = (const float*)d_in[0];
    const int*   ei = (const int*)d_in[1];
    const float* W1 = (const float*)d_in[2];
    const float* b1 = (const float*)d_in[3];
    const float* W2 = (const float*)d_in[4];
    const float* b2 = (const float*)d_in[5];
    float* out = (float*)d_out;

    const int N = in_sizes[0] / F_IN;   // 100000
    const int E = in_sizes[1] / 2;      // 3200000
    const int* row = ei;
    const int* col = ei + E;
    const int NBUCK = (N + BNODES - 1) >> BSH2;   // 391
    const int NEB = (E + EPB - 1) / EPB;          // 391 edge blocks
    const int GB2 = (N + GNOD - 1) / GNOD;        // 782 gemm blocks

    char* w = (char*)d_ws;
    int*   cnt    = (int*)w;   w += (size_t)N * 4;
    int*   bstart = (int*)w;   w += (size_t)(NBMAX + 1) * 4;
    int*   bcur   = (int*)w;   w += (size_t)NBMAX * 4;
    int*   lhists = (int*)w;   w += (size_t)NEB * NBMAX * 4;
    int*   ptr    = (int*)w;   w += (size_t)(N + 1) * 4;
    int*   rows_sorted = (int*)w; w += (size_t)E * 4;
    int*   packed = (int*)w;   w += (size_t)E * 4;
    __half* yp_h  = (__half*)w; w += (size_t)N * HID * 2;
    __half* hp_h  = (__half*)w; w += (size_t)N * HID * 2;
    float* agg2   = (float*)w; w += (size_t)N * HID * 4;

    const int B = 256;
    k_front <<<NEB + GB2, 512, 0, stream>>>(col, lhists, x, W1, yp_h, E, N, NEB);
    k_bscan <<<1, 512, 0, stream>>>(lhists, bstart, bcur, NBUCK, NEB);
    k_bucket<<<NEB, 512, 0, stream>>>(row, col, lhists, bcur, packed, E);
    k_csr   <<<NBUCK, 512, 0, stream>>>(cnt, bstart, packed, ptr, rows_sorted, yp_h, N, NBUCK);
    k_agg<true> <<<((N * 4) + B - 1) / B, B, 0, stream>>>(ptr, rows_sorted, yp_h, cnt, b1, hp_h, nullptr, N);
    k_agg<false><<<((N * 4) + B - 1) / B, B, 0, stream>>>(ptr, rows_sorted, hp_h, cnt, nullptr, nullptr, agg2, N);
    k_final <<<(N + B - 1) / B, B, 0, stream>>>(agg2, W2, b2, out, N);
}